// Round 1
// 213.198 us; speedup vs baseline: 1.0587x; 1.0587x over previous
//
#include <hip/hip_runtime.h>
#include <hip/hip_bf16.h>

typedef __bf16 bf16x8 __attribute__((ext_vector_type(8)));
typedef __bf16 bf16x4 __attribute__((ext_vector_type(4)));
typedef float floatx4 __attribute__((ext_vector_type(4)));

__device__ __forceinline__ float fast_exp2(float x) {
    return __builtin_amdgcn_exp2f(x);  // raw v_exp_f32
}

// barrier that drains LDS only — vmem prefetches stay in flight
__device__ __forceinline__ void lds_barrier() {
    asm volatile("s_waitcnt lgkmcnt(0)\n\ts_barrier" ::: "memory");
}

// async global->LDS, 16B per lane; LDS dest must be lane-linear (wave base + lane*16)
__device__ __forceinline__ void gload16(const __bf16* g, __bf16* l) {
    __builtin_amdgcn_global_load_lds((const __attribute__((address_space(1))) void*)g,
                                     (__attribute__((address_space(3))) void*)l, 16, 0, 0);
}

// ---------------- fused cast fp32 -> bf16 ----------------
__global__ __launch_bounds__(256) void cast_all(const float* __restrict__ hid,
                                                const float* __restrict__ wqkv,
                                                const float* __restrict__ wo,
                                                __bf16* __restrict__ Ah,
                                                __bf16* __restrict__ Wqkvh,
                                                __bf16* __restrict__ Woh) {
    const int n1 = 1048576, n2 = 1310720;
    int i = blockIdx.x * 256 + threadIdx.x;
    const float* in;
    __bf16* out;
    int j;
    if (i < n1) { in = hid; out = Ah; j = i; }
    else if (i < n1 + n2) { in = wqkv; out = Wqkvh; j = i - n1; }
    else { in = wo; out = Woh; j = i - n1 - n2; }
    float4 v = ((const float4*)in)[j];
    bf16x4 o;
    o[0] = (__bf16)v.x; o[1] = (__bf16)v.y; o[2] = (__bf16)v.z; o[3] = (__bf16)v.w;
    ((bf16x4*)out)[j] = o;
}

// ---------------- split-K GEMM: Cpart[z][M][N] (bf16) = A[M][kslice] * B[N][kslice]^T --------
// R6 measured-best body (128x128 tile, BK=64, chunk-fragment LDS, depth-1 reg prefetch,
// lgkm-only barriers) + grid.z = K/2 slice. (unchanged this round)
__global__ __launch_bounds__(256) void gemm_bt_splitk(const __bf16* __restrict__ A,
                                                      const __bf16* __restrict__ B,
                                                      __bf16* __restrict__ C,
                                                      int M, int N, int K) {
    __shared__ __attribute__((aligned(16))) __bf16 As[128 * 64];
    __shared__ __attribute__((aligned(16))) __bf16 Bs[128 * 64];

    int tid = threadIdx.x, lane = tid & 63, w = tid >> 6;
    int wm = (w >> 1) * 64, wn = (w & 1) * 64;
    int bm0 = blockIdx.x * 128, bn0 = blockIdx.y * 128;
    int r = lane & 15, q4 = lane >> 4;
    int rr = lane >> 2, qq = lane & 3;
    int Khalf = K >> 1;
    int kbase = (int)blockIdx.z * Khalf;

    const __bf16* Agp[4];
    const __bf16* Bgp[4];
    __bf16* Asd[4];
    __bf16* Bsd[4];
#pragma unroll
    for (int j = 0; j < 4; j++) {
        int c = w * 4 + j;
        int kk = c >> 3, g = c & 7;
        Agp[j] = A + (size_t)(bm0 + g * 16 + rr) * K + kbase + kk * 32 + qq * 8;
        Bgp[j] = B + (size_t)(bn0 + g * 16 + rr) * K + kbase + kk * 32 + qq * 8;
        Asd[j] = &As[c * 512 + lane * 8];
        Bsd[j] = &Bs[c * 512 + lane * 8];
    }

    floatx4 acc[4][4];
#pragma unroll
    for (int i = 0; i < 4; i++)
#pragma unroll
        for (int j = 0; j < 4; j++) acc[i][j] = (floatx4)0.f;

    bf16x8 ar[4], br[4];
#pragma unroll
    for (int j = 0; j < 4; j++) {
        ar[j] = *(const bf16x8*)Agp[j];
        br[j] = *(const bf16x8*)Bgp[j];
    }

    for (int k0 = 0; k0 < Khalf; k0 += 64) {
        lds_barrier();  // prev iter's frag reads done
#pragma unroll
        for (int j = 0; j < 4; j++) {
            *(bf16x8*)Asd[j] = ar[j];
            *(bf16x8*)Bsd[j] = br[j];
        }
        if (k0 + 64 < Khalf) {
#pragma unroll
            for (int j = 0; j < 4; j++) {
                ar[j] = *(const bf16x8*)(Agp[j] + k0 + 64);
                br[j] = *(const bf16x8*)(Bgp[j] + k0 + 64);
            }
        }
        lds_barrier();  // staged tile visible

#pragma unroll
        for (int kk = 0; kk < 2; kk++) {
            bf16x8 a[4], b[4];
#pragma unroll
            for (int mt = 0; mt < 4; mt++)
                a[mt] = *(const bf16x8*)&As[(kk * 8 + (wm >> 4) + mt) * 512 + r * 32 + q4 * 8];
#pragma unroll
            for (int nt = 0; nt < 4; nt++)
                b[nt] = *(const bf16x8*)&Bs[(kk * 8 + (wn >> 4) + nt) * 512 + r * 32 + q4 * 8];
#pragma unroll
            for (int mt = 0; mt < 4; mt++)
#pragma unroll
                for (int nt = 0; nt < 4; nt++)
                    acc[mt][nt] = __builtin_amdgcn_mfma_f32_16x16x32_bf16(a[mt], b[nt], acc[mt][nt], 0, 0, 0);
        }
    }

    __bf16* Cp = C + (size_t)blockIdx.z * M * N;
#pragma unroll
    for (int mt = 0; mt < 4; mt++)
#pragma unroll
        for (int nt = 0; nt < 4; nt++) {
            int row = bm0 + wm + mt * 16 + q4 * 4;
            int col = bn0 + wn + nt * 16 + r;
#pragma unroll
            for (int i = 0; i < 4; i++)
                Cp[(size_t)(row + i) * N + col] = (__bf16)acc[mt][nt][i];
        }
}

// ---------------- fused RoPE (q,k) + V transpose; adds split-K partials ----------------
// Q pre-scaled by head_dim^-0.5 * log2(e).
// K written XOR-pre-swizzled: Ko[t*256 + (d ^ ((t&7)<<3))] so attn can DMA it linearly
// into LDS and read with the same XOR (bank-conflict-free ds_read_b128).
// V written pre-permuted so attn's LDS V-stage is a pure linear copy:
// Vt'[tile*8192 + (d>>4)*512 + (d&15)*8 + (kv32>>3)*128 + (kv32&7)] = v(kv, d)
__global__ __launch_bounds__(256) void rope_vtrans(const __bf16* __restrict__ qa,
                                                   const __bf16* __restrict__ qb,
                                                   const int* __restrict__ positions,
                                                   __bf16* __restrict__ Qo,
                                                   __bf16* __restrict__ Ko,
                                                   __bf16* __restrict__ Vt) {
    __shared__ float tile[32][33];
    int b = blockIdx.x;
    if (b < 9216) {
        int idx = b * 256 + threadIdx.x;
        int i = idx & 127;
        int th = idx >> 7;
        int head = th % 9;
        int t = th / 9;
        float invf = expf(-(float)i * 0.07195578415606394f);  // 10000^(-i/128)
        float ang = (float)positions[t] * invf;
        float s = sinf(ang), c = cosf(ang);
        size_t off = (size_t)t * 2560 + (head < 8 ? head * 256 : 2048);
        float x1 = (float)qa[off + i] + (float)qb[off + i];
        float x2 = (float)qa[off + i + 128] + (float)qb[off + i + 128];
        if (head < 8) {
            const float qs = 0.09016844f;  // 0.0625 * log2(e)
            __bf16* dst = Qo + (size_t)t * 2048 + head * 256;
            dst[i]       = (__bf16)((x1 * c - x2 * s) * qs);
            dst[i + 128] = (__bf16)((x2 * c + x1 * s) * qs);
        } else {
            int sw = (t & 7) << 3;
            __bf16* dst = Ko + (size_t)t * 256;
            dst[i ^ sw]         = (__bf16)(x1 * c - x2 * s);
            dst[(i + 128) ^ sw] = (__bf16)(x2 * c + x1 * s);
        }
    } else {
        int bb = b - 9216;
        int bt = bb & 63;   // token tile (32 kv)
        int bc = bb >> 6;   // channel tile (32 d)
        int tx = threadIdx.x & 31;
        int ty0 = threadIdx.x >> 5;
#pragma unroll
        for (int ty = ty0; ty < 32; ty += 8) {
            size_t gi = (size_t)(bt * 32 + ty) * 2560 + 2304 + bc * 32 + tx;
            tile[ty][tx] = (float)qa[gi] + (float)qb[gi];
        }
        __syncthreads();
#pragma unroll
        for (int ty = ty0; ty < 32; ty += 8)
            Vt[(size_t)bt * 8192 + (bc * 2 + (ty >> 4)) * 512 + (ty & 15) * 8
               + (tx >> 3) * 128 + (tx & 7)] = (__bf16)tile[tx][ty];
    }
}

// ---------------- Flash attention, softmax-free (fixed m=0) ----------------
// R15: 32 q-rows per wave (2 MFMA row-frags) -> each K/V LDS read feeds 2 MFMAs
// (halves LDS-op density per unit work); K/V staged via global_load_lds width-16
// into double-buffered linear LDS with counted vmcnt(8) (loads in flight across
// barriers); K read with XOR swizzle matching rope's pre-swizzle.
__global__ __launch_bounds__(256, 2) void attn_kernel(const __bf16* __restrict__ Q,
                                                      const __bf16* __restrict__ Kg,
                                                      const __bf16* __restrict__ Vt,
                                                      __bf16* __restrict__ Opart,
                                                      float2* __restrict__ Ml) {
    __shared__ __attribute__((aligned(16))) __bf16 Ks[2][32 * 256];  // linear, XOR on read
    __shared__ __attribute__((aligned(16))) __bf16 Vs[2][16 * 512];  // linear (pre-permuted Vt)
    __shared__ __attribute__((aligned(16))) __bf16 Ps[4][32][40];    // XOR-swizzled cols

    int hg = blockIdx.x;
    int rs = 203 - (int)blockIdx.y;  // heavy-first
    int k, base;
    if (rs < 12)       { k = 1; base = 0; }
    else if (rs < 36)  { k = 2; base = 12; }
    else if (rs < 72)  { k = 3; base = 36; }
    else if (rs < 120) { k = 4; base = 72; }
    else if (rs < 180) { k = 5; base = 120; }
    else               { k = 6; base = 180; }
    int idx = rs - base;
    int s = idx % k;
    int g = (k - 1) * 12 + idx / k;  // q-tile-32 index, 0..63
    int slot = base + idx - s;       // first split-slot of this q-tile

    int start = s * 384;
    int end = g * 32 + 32;
    if (end > start + 384) end = start + 384;
    int ntiles = (end - start) >> 5;  // 1..12, tiles always full 32 kv

    int tid = threadIdx.x, lane = tid & 63, w = tid >> 6;
    int r = lane & 15, q4 = lane >> 4;
    int h = hg * 4 + w;
    int sw = (r & 7) << 3;

    bf16x8 qf[2][8];
#pragma unroll
    for (int qt = 0; qt < 2; qt++) {
        const __bf16* qrow = Q + (size_t)(g * 32 + qt * 16 + r) * 2048 + h * 256 + q4 * 8;
#pragma unroll
        for (int ks = 0; ks < 8; ks++) qf[qt][ks] = *(const bf16x8*)(qrow + ks * 32);
    }

    bf16x8 ones;
#pragma unroll
    for (int i = 0; i < 8; i++) ones[i] = (__bf16)1.0f;

    floatx4 acc[2][16];
#pragma unroll
    for (int qt = 0; qt < 2; qt++)
#pragma unroll
        for (int i = 0; i < 16; i++) acc[qt][i] = (floatx4)0.f;
    floatx4 acc_l[2];
    acc_l[0] = (floatx4)0.f; acc_l[1] = (floatx4)0.f;

    // prologue: DMA tile 0 into buf 0 (8 x global_load_lds dwordx4 per thread-pair)
    {
        const __bf16* kp = Kg + (size_t)start * 256 + tid * 8;
        const __bf16* vp = Vt + (size_t)(start >> 5) * 8192 + tid * 8;
        __bf16* kl = &Ks[0][tid * 8];
        __bf16* vl = &Vs[0][tid * 8];
#pragma unroll
        for (int j = 0; j < 4; j++) {
            gload16(kp + j * 2048, kl + j * 2048);
            gload16(vp + j * 2048, vl + j * 2048);
        }
    }

    for (int t = 0; t < ntiles; t++) {
        int cb = t & 1;
        int kt0 = start + t * 32;
        // all waves done READING buf[cb^1] (consumed by MFMA deps) -> safe to overwrite
        asm volatile("s_barrier" ::: "memory");
        if (t + 1 < ntiles) {
            int kt1 = kt0 + 32;
            const __bf16* kp = Kg + (size_t)kt1 * 256 + tid * 8;
            const __bf16* vp = Vt + (size_t)(kt1 >> 5) * 8192 + tid * 8;
            __bf16* kl = &Ks[cb ^ 1][tid * 8];
            __bf16* vl = &Vs[cb ^ 1][tid * 8];
#pragma unroll
            for (int j = 0; j < 4; j++) {
                gload16(kp + j * 2048, kl + j * 2048);
                gload16(vp + j * 2048, vl + j * 2048);
            }
            // wait current tile's 8 DMAs only; next tile's 8 stay in flight
            asm volatile("s_waitcnt vmcnt(8)\n\ts_barrier" ::: "memory");
        } else {
            asm volatile("s_waitcnt vmcnt(0)\n\ts_barrier" ::: "memory");
        }

        // S = Q K^T (exp2 units), 2 q-frags per K-frag read
        floatx4 sc[2][2];
        sc[0][0] = (floatx4)0.f; sc[0][1] = (floatx4)0.f;
        sc[1][0] = (floatx4)0.f; sc[1][1] = (floatx4)0.f;
#pragma unroll
        for (int ks = 0; ks < 8; ks++) {
#pragma unroll
            for (int nt = 0; nt < 2; nt++) {
                bf16x8 kf = *(const bf16x8*)&Ks[cb][(nt * 16 + r) * 256 + ((ks * 32 + q4 * 8) ^ sw)];
#pragma unroll
                for (int qt = 0; qt < 2; qt++)
                    sc[qt][nt] = __builtin_amdgcn_mfma_f32_16x16x32_bf16(qf[qt][ks], kf, sc[qt][nt], 0, 0, 0);
            }
        }
        if (kt0 + 31 > g * 32) {  // causal mask (block-uniform branch)
#pragma unroll
            for (int qt = 0; qt < 2; qt++) {
                int qbase = g * 32 + qt * 16 + q4 * 4;
#pragma unroll
                for (int nt = 0; nt < 2; nt++) {
                    int kpos = kt0 + nt * 16 + r;
#pragma unroll
                    for (int i = 0; i < 4; i++)
                        if (kpos > qbase + i) sc[qt][nt][i] = -3e38f;
                }
            }
        }

        // p = exp2(s) — no max subtraction, no rescale (bounded scores)
#pragma unroll
        for (int qt = 0; qt < 2; qt++)
#pragma unroll
            for (int nt = 0; nt < 2; nt++)
#pragma unroll
                for (int i = 0; i < 4; i++)
                    Ps[w][qt * 16 + q4 * 4 + i][(nt * 16 + r) ^ (q4 << 3)] = (__bf16)fast_exp2(sc[qt][nt][i]);
        __builtin_amdgcn_wave_barrier();
        bf16x8 pf[2];
#pragma unroll
        for (int qt = 0; qt < 2; qt++)
            pf[qt] = *(const bf16x8*)&Ps[w][qt * 16 + r][(q4 * 8) ^ ((r >> 2) << 3)];
        __builtin_amdgcn_wave_barrier();

        // O += P V; l += P . 1 — 2 MFMAs per V-frag read
#pragma unroll
        for (int n16 = 0; n16 < 16; n16++) {
            bf16x8 vf = *(const bf16x8*)&Vs[cb][n16 * 512 + lane * 8];
            acc[0][n16] = __builtin_amdgcn_mfma_f32_16x16x32_bf16(pf[0], vf, acc[0][n16], 0, 0, 0);
            acc[1][n16] = __builtin_amdgcn_mfma_f32_16x16x32_bf16(pf[1], vf, acc[1][n16], 0, 0, 0);
        }
        acc_l[0] = __builtin_amdgcn_mfma_f32_16x16x32_bf16(pf[0], ones, acc_l[0], 0, 0, 0);
        acc_l[1] = __builtin_amdgcn_mfma_f32_16x16x32_bf16(pf[1], ones, acc_l[1], 0, 0, 0);
    }

    // unnormalized partials (m = 0 for all splits); 256 rows per split-slot
    size_t base_row = (size_t)(slot + s) * 256 + hg * 128 + w * 32;
#pragma unroll
    for (int qt = 0; qt < 2; qt++)
#pragma unroll
        for (int n16 = 0; n16 < 16; n16++)
#pragma unroll
            for (int i = 0; i < 4; i++)
                Opart[(base_row + qt * 16 + q4 * 4 + i) * 256 + n16 * 16 + r] = (__bf16)acc[qt][n16][i];
    if (r == 0) {
#pragma unroll
        for (int qt = 0; qt < 2; qt++)
#pragma unroll
            for (int i = 0; i < 4; i++)
                Ml[base_row + qt * 16 + q4 * 4 + i] = make_float2(0.f, acc_l[qt][i]);
    }
}

// ---------------- combine partials -> attn output (bf16 [2048][2048]) ----------------
__global__ __launch_bounds__(256) void combine_kernel(const __bf16* __restrict__ Opart,
                                                      const float2* __restrict__ Ml,
                                                      __bf16* __restrict__ attnb) {
    int wid = blockIdx.x * 4 + (threadIdx.x >> 6);  // (t,h)
    int lane = threadIdx.x & 63;
    int t = wid >> 3, h = wid & 7;
    int g = t >> 5, r32 = t & 31;
    int qt = r32 >> 4, row16 = r32 & 15;
    int hg = h >> 2, w = h & 3;
    int k = g / 12 + 1;                              // nsp = ceil((g+1)/12)
    int fg = 6 * k * (k - 1) + (g - 12 * (k - 1)) * k;

    float ls[6];
    size_t rbase[6];
    for (int s = 0; s < k; s++) {
        rbase[s] = (size_t)(fg + s) * 256 + hg * 128 + w * 32 + qt * 16 + row16;
        ls[s] = Ml[rbase[s]].y;
    }
    float L = 0.f;
    float o[4] = {0.f, 0.f, 0.f, 0.f};
    for (int s = 0; s < k; s++) {
        L += ls[s];
        bf16x4 v = *(const bf16x4*)&Opart[rbase[s] * 256 + lane * 4];
#pragma unroll
        for (int j = 0; j < 4; j++) o[j] += (float)v[j];
    }
    float inv = 1.f / L;
    bf16x4 ov;
#pragma unroll
    for (int j = 0; j < 4; j++) ov[j] = (__bf16)(o[j] * inv);
    *(bf16x4*)&attnb[(size_t)t * 2048 + h * 256 + lane * 4] = ov;
}

// ---------------- add split-K partials -> fp32 output ----------------
__global__ __launch_bounds__(256) void add_out(const __bf16* __restrict__ p0,
                                               const __bf16* __restrict__ p1,
                                               float* __restrict__ out, int n4) {
    int i = blockIdx.x * 256 + threadIdx.x;
    if (i < n4) {
        bf16x4 a = ((const bf16x4*)p0)[i];
        bf16x4 b = ((const bf16x4*)p1)[i];
        float4 o;
        o.x = (float)a[0] + (float)b[0];
        o.y = (float)a[1] + (float)b[1];
        o.z = (float)a[2] + (float)b[2];
        o.w = (float)a[3] + (float)b[3];
        ((float4*)out)[i] = o;
    }
}

extern "C" void kernel_launch(void* const* d_in, const int* in_sizes, int n_in,
                              void* d_out, int out_size, void* d_ws, size_t ws_size,
                              hipStream_t stream) {
    const int* positions = (const int*)d_in[0];
    const float* hidden  = (const float*)d_in[1];
    const float* Wqkv    = (const float*)d_in[2];
    const float* Wo      = (const float*)d_in[3];
    float* out = (float*)d_out;

    char* ws = (char*)d_ws;
    const size_t MB = 1024 * 1024;
    // [0,8)   Ah (bf16 hidden) -> dead after gemm1, reused as attnb
    // [8,16)  Woh
    // [16,24) Qb   [24,25) Kb (pre-swizzled)   [25,26) Vtb (pre-permuted tile-blocked)
    // [26,36) Wqkvh  --+ dead after gemm1/rope: Opart (25.5 MB at 26, 204 slots x 256 rows)
    // [36,56) qkvp (two 10 MB split-K slices); Ml (418 KB at 52, inside dead qkvp)
    // after combine: Opart dead -> gp (two 8 MB gemm2 partials at 26)
    __bf16* Ah    = (__bf16*)(ws + 0 * MB);
    __bf16* Woh   = (__bf16*)(ws + 8 * MB);
    __bf16* Qb    = (__bf16*)(ws + 16 * MB);
    __bf16* Kb    = (__bf16*)(ws + 24 * MB);
    __bf16* Vtb   = (__bf16*)(ws + 25 * MB);
    __bf16* Wqkvh = (__bf16*)(ws + 26 * MB);
    __bf16* qkvp  = (__bf16*)(ws + 36 * MB);
    __bf16* qkv_a = qkvp;
    __bf16* qkv_b = qkvp + (size_t)2048 * 2560;
    __bf16* Opart = (__bf16*)(ws + 26 * MB);
    float2* Ml    = (float2*)(ws + 52 * MB);
    __bf16* attnb = Ah;
    __bf16* gp    = (__bf16*)(ws + 26 * MB);

    cast_all<<<13312, 256, 0, stream>>>(hidden, Wqkv, Wo, Ah, Wqkvh, Woh);

    // qkv partials = hidden @ Wqkv^T, split-K x2 (16-iter chains, 640 blocks)
    gemm_bt_splitk<<<dim3(16, 20, 2), 256, 0, stream>>>(Ah, Wqkvh, qkvp, 2048, 2560, 2048);

    rope_vtrans<<<9728, 256, 0, stream>>>(qkv_a, qkv_b, positions, Qb, Kb, Vtb);

    attn_kernel<<<dim3(2, 204), 256, 0, stream>>>(Qb, Kb, Vtb, Opart, Ml);
    combine_kernel<<<4096, 256, 0, stream>>>(Opart, Ml, attnb);

    // out partials = attn @ Wo^T, split-K x2 (512 blocks), then add
    gemm_bt_splitk<<<dim3(16, 16, 2), 256, 0, stream>>>(attnb, Woh, gp, 2048, 2048, 2048);
    add_out<<<4096, 256, 0, stream>>>(gp, gp + (size_t)2048 * 2048, out, 1048576);
}

// Round 2
// 212.978 us; speedup vs baseline: 1.0598x; 1.0010x over previous
//
#include <hip/hip_runtime.h>
#include <hip/hip_bf16.h>

typedef __bf16 bf16x8 __attribute__((ext_vector_type(8)));
typedef __bf16 bf16x4 __attribute__((ext_vector_type(4)));
typedef float floatx4 __attribute__((ext_vector_type(4)));

__device__ __forceinline__ float fast_exp2(float x) {
    return __builtin_amdgcn_exp2f(x);  // raw v_exp_f32
}

// barrier that drains LDS only — vmem prefetches stay in flight
__device__ __forceinline__ void lds_barrier() {
    asm volatile("s_waitcnt lgkmcnt(0)\n\ts_barrier" ::: "memory");
}

// async global->LDS, 16B per lane; LDS dest is wave-uniform base (HW adds lane*16)
__device__ __forceinline__ void gload16(const __bf16* g, __bf16* l) {
    __builtin_amdgcn_global_load_lds((const __attribute__((address_space(1))) void*)g,
                                     (__attribute__((address_space(3))) void*)l, 16, 0, 0);
}

// ---------------- fused cast fp32 -> bf16 ----------------
__global__ __launch_bounds__(256) void cast_all(const float* __restrict__ hid,
                                                const float* __restrict__ wqkv,
                                                const float* __restrict__ wo,
                                                __bf16* __restrict__ Ah,
                                                __bf16* __restrict__ Wqkvh,
                                                __bf16* __restrict__ Woh) {
    const int n1 = 1048576, n2 = 1310720;
    int i = blockIdx.x * 256 + threadIdx.x;
    const float* in;
    __bf16* out;
    int j;
    if (i < n1) { in = hid; out = Ah; j = i; }
    else if (i < n1 + n2) { in = wqkv; out = Wqkvh; j = i - n1; }
    else { in = wo; out = Woh; j = i - n1 - n2; }
    float4 v = ((const float4*)in)[j];
    bf16x4 o;
    o[0] = (__bf16)v.x; o[1] = (__bf16)v.y; o[2] = (__bf16)v.z; o[3] = (__bf16)v.w;
    ((bf16x4*)out)[j] = o;
}

// ---------------- split-K GEMM: Cpart[z][M][N] (bf16) = A[M][kslice] * B[N][kslice]^T --------
// R16: staging via global_load_lds width-16 (m97-exact single-buffer: barrier, 8 DMAs,
// vmcnt(0)+barrier, compute). Chunk-fragment LDS layout unchanged (it is lane-linear:
// wave base c*1024B + lane*16B), so ds_read/MFMA/epilogue identical to R6 body.
// Removes 8 ds_write_b128/wave/tile (LDS pipe) + 32 staging VGPRs.
__global__ __launch_bounds__(256) void gemm_bt_splitk(const __bf16* __restrict__ A,
                                                      const __bf16* __restrict__ B,
                                                      __bf16* __restrict__ C,
                                                      int M, int N, int K) {
    __shared__ __attribute__((aligned(16))) __bf16 As[128 * 64];
    __shared__ __attribute__((aligned(16))) __bf16 Bs[128 * 64];

    int tid = threadIdx.x, lane = tid & 63, w = tid >> 6;
    int wm = (w >> 1) * 64, wn = (w & 1) * 64;
    int bm0 = blockIdx.x * 128, bn0 = blockIdx.y * 128;
    int r = lane & 15, q4 = lane >> 4;
    int rr = lane >> 2, qq = lane & 3;
    int Khalf = K >> 1;
    int kbase = (int)blockIdx.z * Khalf;

    const __bf16* Agp[4];
    const __bf16* Bgp[4];
    __bf16* Asd[4];
    __bf16* Bsd[4];
#pragma unroll
    for (int j = 0; j < 4; j++) {
        int c = w * 4 + j;
        int kk = c >> 3, g = c & 7;
        Agp[j] = A + (size_t)(bm0 + g * 16 + rr) * K + kbase + kk * 32 + qq * 8;
        Bgp[j] = B + (size_t)(bn0 + g * 16 + rr) * K + kbase + kk * 32 + qq * 8;
        Asd[j] = &As[c * 512];  // wave-uniform DMA base; HW writes lane*16B
        Bsd[j] = &Bs[c * 512];
    }

    floatx4 acc[4][4];
#pragma unroll
    for (int i = 0; i < 4; i++)
#pragma unroll
        for (int j = 0; j < 4; j++) acc[i][j] = (floatx4)0.f;

    for (int k0 = 0; k0 < Khalf; k0 += 64) {
        asm volatile("s_barrier" ::: "memory");  // prev iter's frag reads done
#pragma unroll
        for (int j = 0; j < 4; j++) {
            gload16(Agp[j] + k0, Asd[j]);
            gload16(Bgp[j] + k0, Bsd[j]);
        }
        asm volatile("s_waitcnt vmcnt(0)\n\ts_barrier" ::: "memory");  // tile visible

#pragma unroll
        for (int kk = 0; kk < 2; kk++) {
            bf16x8 a[4], b[4];
#pragma unroll
            for (int mt = 0; mt < 4; mt++)
                a[mt] = *(const bf16x8*)&As[(kk * 8 + (wm >> 4) + mt) * 512 + r * 32 + q4 * 8];
#pragma unroll
            for (int nt = 0; nt < 4; nt++)
                b[nt] = *(const bf16x8*)&Bs[(kk * 8 + (wn >> 4) + nt) * 512 + r * 32 + q4 * 8];
#pragma unroll
            for (int mt = 0; mt < 4; mt++)
#pragma unroll
                for (int nt = 0; nt < 4; nt++)
                    acc[mt][nt] = __builtin_amdgcn_mfma_f32_16x16x32_bf16(a[mt], b[nt], acc[mt][nt], 0, 0, 0);
        }
    }

    __bf16* Cp = C + (size_t)blockIdx.z * M * N;
#pragma unroll
    for (int mt = 0; mt < 4; mt++)
#pragma unroll
        for (int nt = 0; nt < 4; nt++) {
            int row = bm0 + wm + mt * 16 + q4 * 4;
            int col = bn0 + wn + nt * 16 + r;
#pragma unroll
            for (int i = 0; i < 4; i++)
                Cp[(size_t)(row + i) * N + col] = (__bf16)acc[mt][nt][i];
        }
}

// ---------------- fused RoPE (q,k) + V transpose; adds split-K partials ----------------
// Q pre-scaled by head_dim^-0.5 * log2(e).
// K written XOR-pre-swizzled: Ko[t*256 + (d ^ ((t&7)<<3))] so attn can DMA it linearly
// into LDS and read with the same XOR (bank-conflict-free ds_read_b128).
// V written pre-permuted so attn's LDS V-stage is a pure linear copy:
// Vt'[tile*8192 + (d>>4)*512 + (d&15)*8 + (kv32>>3)*128 + (kv32&7)] = v(kv, d)
__global__ __launch_bounds__(256) void rope_vtrans(const __bf16* __restrict__ qa,
                                                   const __bf16* __restrict__ qb,
                                                   const int* __restrict__ positions,
                                                   __bf16* __restrict__ Qo,
                                                   __bf16* __restrict__ Ko,
                                                   __bf16* __restrict__ Vt) {
    __shared__ float tile[32][33];
    int b = blockIdx.x;
    if (b < 9216) {
        int idx = b * 256 + threadIdx.x;
        int i = idx & 127;
        int th = idx >> 7;
        int head = th % 9;
        int t = th / 9;
        float invf = expf(-(float)i * 0.07195578415606394f);  // 10000^(-i/128)
        float ang = (float)positions[t] * invf;
        float s = sinf(ang), c = cosf(ang);
        size_t off = (size_t)t * 2560 + (head < 8 ? head * 256 : 2048);
        float x1 = (float)qa[off + i] + (float)qb[off + i];
        float x2 = (float)qa[off + i + 128] + (float)qb[off + i + 128];
        if (head < 8) {
            const float qs = 0.09016844f;  // 0.0625 * log2(e)
            __bf16* dst = Qo + (size_t)t * 2048 + head * 256;
            dst[i]       = (__bf16)((x1 * c - x2 * s) * qs);
            dst[i + 128] = (__bf16)((x2 * c + x1 * s) * qs);
        } else {
            int sw = (t & 7) << 3;
            __bf16* dst = Ko + (size_t)t * 256;
            dst[i ^ sw]         = (__bf16)(x1 * c - x2 * s);
            dst[(i + 128) ^ sw] = (__bf16)(x2 * c + x1 * s);
        }
    } else {
        int bb = b - 9216;
        int bt = bb & 63;   // token tile (32 kv)
        int bc = bb >> 6;   // channel tile (32 d)
        int tx = threadIdx.x & 31;
        int ty0 = threadIdx.x >> 5;
#pragma unroll
        for (int ty = ty0; ty < 32; ty += 8) {
            size_t gi = (size_t)(bt * 32 + ty) * 2560 + 2304 + bc * 32 + tx;
            tile[ty][tx] = (float)qa[gi] + (float)qb[gi];
        }
        __syncthreads();
#pragma unroll
        for (int ty = ty0; ty < 32; ty += 8)
            Vt[(size_t)bt * 8192 + (bc * 2 + (ty >> 4)) * 512 + (ty & 15) * 8
               + (tx >> 3) * 128 + (tx & 7)] = (__bf16)tile[tx][ty];
    }
}

// ---------------- Flash attention, softmax-free (fixed m=0) ----------------
// R15: 32 q-rows per wave (2 MFMA row-frags) -> each K/V LDS read feeds 2 MFMAs
// (halves LDS-op density per unit work); K/V staged via global_load_lds width-16
// into double-buffered linear LDS with counted vmcnt(8) (loads in flight across
// barriers); K read with XOR swizzle matching rope's pre-swizzle.
__global__ __launch_bounds__(256, 2) void attn_kernel(const __bf16* __restrict__ Q,
                                                      const __bf16* __restrict__ Kg,
                                                      const __bf16* __restrict__ Vt,
                                                      __bf16* __restrict__ Opart,
                                                      float2* __restrict__ Ml) {
    __shared__ __attribute__((aligned(16))) __bf16 Ks[2][32 * 256];  // linear, XOR on read
    __shared__ __attribute__((aligned(16))) __bf16 Vs[2][16 * 512];  // linear (pre-permuted Vt)
    __shared__ __attribute__((aligned(16))) __bf16 Ps[4][32][40];    // XOR-swizzled cols

    int hg = blockIdx.x;
    int rs = 203 - (int)blockIdx.y;  // heavy-first
    int k, base;
    if (rs < 12)       { k = 1; base = 0; }
    else if (rs < 36)  { k = 2; base = 12; }
    else if (rs < 72)  { k = 3; base = 36; }
    else if (rs < 120) { k = 4; base = 72; }
    else if (rs < 180) { k = 5; base = 120; }
    else               { k = 6; base = 180; }
    int idx = rs - base;
    int s = idx % k;
    int g = (k - 1) * 12 + idx / k;  // q-tile-32 index, 0..63
    int slot = base + idx - s;       // first split-slot of this q-tile

    int start = s * 384;
    int end = g * 32 + 32;
    if (end > start + 384) end = start + 384;
    int ntiles = (end - start) >> 5;  // 1..12, tiles always full 32 kv

    int tid = threadIdx.x, lane = tid & 63, w = tid >> 6;
    int r = lane & 15, q4 = lane >> 4;
    int h = hg * 4 + w;
    int sw = (r & 7) << 3;

    bf16x8 qf[2][8];
#pragma unroll
    for (int qt = 0; qt < 2; qt++) {
        const __bf16* qrow = Q + (size_t)(g * 32 + qt * 16 + r) * 2048 + h * 256 + q4 * 8;
#pragma unroll
        for (int ks = 0; ks < 8; ks++) qf[qt][ks] = *(const bf16x8*)(qrow + ks * 32);
    }

    bf16x8 ones;
#pragma unroll
    for (int i = 0; i < 8; i++) ones[i] = (__bf16)1.0f;

    floatx4 acc[2][16];
#pragma unroll
    for (int qt = 0; qt < 2; qt++)
#pragma unroll
        for (int i = 0; i < 16; i++) acc[qt][i] = (floatx4)0.f;
    floatx4 acc_l[2];
    acc_l[0] = (floatx4)0.f; acc_l[1] = (floatx4)0.f;

    // prologue: DMA tile 0 into buf 0 (8 x global_load_lds dwordx4 per thread-pair)
    {
        const __bf16* kp = Kg + (size_t)start * 256 + tid * 8;
        const __bf16* vp = Vt + (size_t)(start >> 5) * 8192 + tid * 8;
        __bf16* kl = &Ks[0][tid * 8];
        __bf16* vl = &Vs[0][tid * 8];
#pragma unroll
        for (int j = 0; j < 4; j++) {
            gload16(kp + j * 2048, kl + j * 2048);
            gload16(vp + j * 2048, vl + j * 2048);
        }
    }

    for (int t = 0; t < ntiles; t++) {
        int cb = t & 1;
        int kt0 = start + t * 32;
        // all waves done READING buf[cb^1] (consumed by MFMA deps) -> safe to overwrite
        asm volatile("s_barrier" ::: "memory");
        if (t + 1 < ntiles) {
            int kt1 = kt0 + 32;
            const __bf16* kp = Kg + (size_t)kt1 * 256 + tid * 8;
            const __bf16* vp = Vt + (size_t)(kt1 >> 5) * 8192 + tid * 8;
            __bf16* kl = &Ks[cb ^ 1][tid * 8];
            __bf16* vl = &Vs[cb ^ 1][tid * 8];
#pragma unroll
            for (int j = 0; j < 4; j++) {
                gload16(kp + j * 2048, kl + j * 2048);
                gload16(vp + j * 2048, vl + j * 2048);
            }
            // wait current tile's 8 DMAs only; next tile's 8 stay in flight
            asm volatile("s_waitcnt vmcnt(8)\n\ts_barrier" ::: "memory");
        } else {
            asm volatile("s_waitcnt vmcnt(0)\n\ts_barrier" ::: "memory");
        }

        // S = Q K^T (exp2 units), 2 q-frags per K-frag read
        floatx4 sc[2][2];
        sc[0][0] = (floatx4)0.f; sc[0][1] = (floatx4)0.f;
        sc[1][0] = (floatx4)0.f; sc[1][1] = (floatx4)0.f;
#pragma unroll
        for (int ks = 0; ks < 8; ks++) {
#pragma unroll
            for (int nt = 0; nt < 2; nt++) {
                bf16x8 kf = *(const bf16x8*)&Ks[cb][(nt * 16 + r) * 256 + ((ks * 32 + q4 * 8) ^ sw)];
#pragma unroll
                for (int qt = 0; qt < 2; qt++)
                    sc[qt][nt] = __builtin_amdgcn_mfma_f32_16x16x32_bf16(qf[qt][ks], kf, sc[qt][nt], 0, 0, 0);
            }
        }
        if (kt0 + 31 > g * 32) {  // causal mask (block-uniform branch)
#pragma unroll
            for (int qt = 0; qt < 2; qt++) {
                int qbase = g * 32 + qt * 16 + q4 * 4;
#pragma unroll
                for (int nt = 0; nt < 2; nt++) {
                    int kpos = kt0 + nt * 16 + r;
#pragma unroll
                    for (int i = 0; i < 4; i++)
                        if (kpos > qbase + i) sc[qt][nt][i] = -3e38f;
                }
            }
        }

        // p = exp2(s) — no max subtraction, no rescale (bounded scores)
#pragma unroll
        for (int qt = 0; qt < 2; qt++)
#pragma unroll
            for (int nt = 0; nt < 2; nt++)
#pragma unroll
                for (int i = 0; i < 4; i++)
                    Ps[w][qt * 16 + q4 * 4 + i][(nt * 16 + r) ^ (q4 << 3)] = (__bf16)fast_exp2(sc[qt][nt][i]);
        __builtin_amdgcn_wave_barrier();
        bf16x8 pf[2];
#pragma unroll
        for (int qt = 0; qt < 2; qt++)
            pf[qt] = *(const bf16x8*)&Ps[w][qt * 16 + r][(q4 * 8) ^ ((r >> 2) << 3)];
        __builtin_amdgcn_wave_barrier();

        // O += P V; l += P . 1 — 2 MFMAs per V-frag read
#pragma unroll
        for (int n16 = 0; n16 < 16; n16++) {
            bf16x8 vf = *(const bf16x8*)&Vs[cb][n16 * 512 + lane * 8];
            acc[0][n16] = __builtin_amdgcn_mfma_f32_16x16x32_bf16(pf[0], vf, acc[0][n16], 0, 0, 0);
            acc[1][n16] = __builtin_amdgcn_mfma_f32_16x16x32_bf16(pf[1], vf, acc[1][n16], 0, 0, 0);
        }
        acc_l[0] = __builtin_amdgcn_mfma_f32_16x16x32_bf16(pf[0], ones, acc_l[0], 0, 0, 0);
        acc_l[1] = __builtin_amdgcn_mfma_f32_16x16x32_bf16(pf[1], ones, acc_l[1], 0, 0, 0);
    }

    // unnormalized partials (m = 0 for all splits); 256 rows per split-slot
    size_t base_row = (size_t)(slot + s) * 256 + hg * 128 + w * 32;
#pragma unroll
    for (int qt = 0; qt < 2; qt++)
#pragma unroll
        for (int n16 = 0; n16 < 16; n16++)
#pragma unroll
            for (int i = 0; i < 4; i++)
                Opart[(base_row + qt * 16 + q4 * 4 + i) * 256 + n16 * 16 + r] = (__bf16)acc[qt][n16][i];
    if (r == 0) {
#pragma unroll
        for (int qt = 0; qt < 2; qt++)
#pragma unroll
            for (int i = 0; i < 4; i++)
                Ml[base_row + qt * 16 + q4 * 4 + i] = make_float2(0.f, acc_l[qt][i]);
    }
}

// ---------------- combine partials -> attn output (bf16 [2048][2048]) ----------------
__global__ __launch_bounds__(256) void combine_kernel(const __bf16* __restrict__ Opart,
                                                      const float2* __restrict__ Ml,
                                                      __bf16* __restrict__ attnb) {
    int wid = blockIdx.x * 4 + (threadIdx.x >> 6);  // (t,h)
    int lane = threadIdx.x & 63;
    int t = wid >> 3, h = wid & 7;
    int g = t >> 5, r32 = t & 31;
    int qt = r32 >> 4, row16 = r32 & 15;
    int hg = h >> 2, w = h & 3;
    int k = g / 12 + 1;                              // nsp = ceil((g+1)/12)
    int fg = 6 * k * (k - 1) + (g - 12 * (k - 1)) * k;

    float ls[6];
    size_t rbase[6];
    for (int s = 0; s < k; s++) {
        rbase[s] = (size_t)(fg + s) * 256 + hg * 128 + w * 32 + qt * 16 + row16;
        ls[s] = Ml[rbase[s]].y;
    }
    float L = 0.f;
    float o[4] = {0.f, 0.f, 0.f, 0.f};
    for (int s = 0; s < k; s++) {
        L += ls[s];
        bf16x4 v = *(const bf16x4*)&Opart[rbase[s] * 256 + lane * 4];
#pragma unroll
        for (int j = 0; j < 4; j++) o[j] += (float)v[j];
    }
    float inv = 1.f / L;
    bf16x4 ov;
#pragma unroll
    for (int j = 0; j < 4; j++) ov[j] = (__bf16)(o[j] * inv);
    *(bf16x4*)&attnb[(size_t)t * 2048 + h * 256 + lane * 4] = ov;
}

// ---------------- add split-K partials -> fp32 output ----------------
__global__ __launch_bounds__(256) void add_out(const __bf16* __restrict__ p0,
                                               const __bf16* __restrict__ p1,
                                               float* __restrict__ out, int n4) {
    int i = blockIdx.x * 256 + threadIdx.x;
    if (i < n4) {
        bf16x4 a = ((const bf16x4*)p0)[i];
        bf16x4 b = ((const bf16x4*)p1)[i];
        float4 o;
        o.x = (float)a[0] + (float)b[0];
        o.y = (float)a[1] + (float)b[1];
        o.z = (float)a[2] + (float)b[2];
        o.w = (float)a[3] + (float)b[3];
        ((float4*)out)[i] = o;
    }
}

extern "C" void kernel_launch(void* const* d_in, const int* in_sizes, int n_in,
                              void* d_out, int out_size, void* d_ws, size_t ws_size,
                              hipStream_t stream) {
    const int* positions = (const int*)d_in[0];
    const float* hidden  = (const float*)d_in[1];
    const float* Wqkv    = (const float*)d_in[2];
    const float* Wo      = (const float*)d_in[3];
    float* out = (float*)d_out;

    char* ws = (char*)d_ws;
    const size_t MB = 1024 * 1024;
    // [0,8)   Ah (bf16 hidden) -> dead after gemm1, reused as attnb
    // [8,16)  Woh
    // [16,24) Qb   [24,25) Kb (pre-swizzled)   [25,26) Vtb (pre-permuted tile-blocked)
    // [26,36) Wqkvh  --+ dead after gemm1/rope: Opart (25.5 MB at 26, 204 slots x 256 rows)
    // [36,56) qkvp (two 10 MB split-K slices); Ml (418 KB at 52, inside dead qkvp)
    // after combine: Opart dead -> gp (two 8 MB gemm2 partials at 26)
    __bf16* Ah    = (__bf16*)(ws + 0 * MB);
    __bf16* Woh   = (__bf16*)(ws + 8 * MB);
    __bf16* Qb    = (__bf16*)(ws + 16 * MB);
    __bf16* Kb    = (__bf16*)(ws + 24 * MB);
    __bf16* Vtb   = (__bf16*)(ws + 25 * MB);
    __bf16* Wqkvh = (__bf16*)(ws + 26 * MB);
    __bf16* qkvp  = (__bf16*)(ws + 36 * MB);
    __bf16* qkv_a = qkvp;
    __bf16* qkv_b = qkvp + (size_t)2048 * 2560;
    __bf16* Opart = (__bf16*)(ws + 26 * MB);
    float2* Ml    = (float2*)(ws + 52 * MB);
    __bf16* attnb = Ah;
    __bf16* gp    = (__bf16*)(ws + 26 * MB);

    cast_all<<<13312, 256, 0, stream>>>(hidden, Wqkv, Wo, Ah, Wqkvh, Woh);

    // qkv partials = hidden @ Wqkv^T, split-K x2 (16-iter chains, 640 blocks)
    gemm_bt_splitk<<<dim3(16, 20, 2), 256, 0, stream>>>(Ah, Wqkvh, qkvp, 2048, 2560, 2048);

    rope_vtrans<<<9728, 256, 0, stream>>>(qkv_a, qkv_b, positions, Qb, Kb, Vtb);

    attn_kernel<<<dim3(2, 204), 256, 0, stream>>>(Qb, Kb, Vtb, Opart, Ml);
    combine_kernel<<<4096, 256, 0, stream>>>(Opart, Ml, attnb);

    // out partials = attn @ Wo^T, split-K x2 (512 blocks), then add
    gemm_bt_splitk<<<dim3(16, 16, 2), 256, 0, stream>>>(attnb, Woh, gp, 2048, 2048, 2048);
    add_out<<<4096, 256, 0, stream>>>(gp, gp + (size_t)2048 * 2048, out, 1048576);
}